// Round 2
// baseline (381.285 us; speedup 1.0000x reference)
//
#include <hip/hip_runtime.h>

// Sizes (fixed by the problem)
#define B 2
#define N 512
#define DIN 256
#define H 16
#define DOUT 128
#define ROWS (B * N)   // 1024

// -------- Kernel A: per row (b*512+n): LN + proj(a,bq) + T = a @ Wd --------
// Writes bq (fp32, ROWS x 16) and T (fp32, ROWS x 128 x 16) into workspace.
__global__ __launch_bounds__(256) void kA(const float* __restrict__ feats,
                                          const float* __restrict__ gamma,
                                          const float* __restrict__ beta,
                                          const float* __restrict__ Win,
                                          const float* __restrict__ bin,
                                          const float* __restrict__ Wout,
                                          float* __restrict__ bq_ws,
                                          float* __restrict__ T_ws) {
    const int row = blockIdx.x;       // 0..1023
    const int t = threadIdx.x;        // 0..255

    __shared__ float sx[DIN];         // normalized row
    __shared__ float pp[256];         // proj partials
    __shared__ float pa[H];           // a (first 16 of proj)
    __shared__ float redA[4], redB[4];

    // ---- load one element per thread, LayerNorm over 256 ----
    const float x = feats[row * DIN + t];

    float s = x;
#pragma unroll
    for (int o = 32; o; o >>= 1) s += __shfl_xor(s, o, 64);
    if ((t & 63) == 0) redA[t >> 6] = s;
    __syncthreads();
    const float mean = (redA[0] + redA[1] + redA[2] + redA[3]) * (1.0f / 256.0f);

    const float dx = x - mean;
    float s2 = dx * dx;
#pragma unroll
    for (int o = 32; o; o >>= 1) s2 += __shfl_xor(s2, o, 64);
    if ((t & 63) == 0) redB[t >> 6] = s2;
    __syncthreads();
    const float var = (redB[0] + redB[1] + redB[2] + redB[3]) * (1.0f / 256.0f);
    const float rstd = rsqrtf(var + 1e-5f);

    const float xn = dx * rstd * gamma[t] + beta[t];
    sx[t] = xn;
    __syncthreads();

    // ---- proj = xn @ Win (+ bin): 256 threads, k = t&31, seg = t>>5 ----
    {
        const int k = t & 31;
        const int seg = t >> 5;       // 8 segments of 32 j each
        const int j0 = seg * 32;
        float partial = 0.0f;
#pragma unroll
        for (int j = 0; j < 32; j++) {
            partial = fmaf(sx[j0 + j], Win[(j0 + j) * 32 + k], partial);
        }
        pp[t] = partial;
    }
    __syncthreads();

    if (t < 32) {
        float pr = bin[t];
#pragma unroll
        for (int h = 0; h < 8; h++) pr += pp[h * 32 + t];
        if (t < H) pa[t] = pr;                         // a
        else bq_ws[row * H + (t - H)] = pr;            // bq -> workspace
    }
    __syncthreads();

    // ---- T[d][q] = sum_p a[p] * Wout[d*256 + p*16 + q] ----
    // thread t: d = t>>1, q-half = (t&1)*8 -> 8 outputs
    {
        const int d = t >> 1;
        const int q0 = (t & 1) * 8;
        float acc[8];
#pragma unroll
        for (int j = 0; j < 8; j++) acc[j] = 0.0f;
        const float* wp = Wout + d * 256 + q0;
#pragma unroll
        for (int p = 0; p < 16; p++) {
            const float av = pa[p];
            const float4* w4 = reinterpret_cast<const float4*>(wp + p * 16);
            const float4 w0 = w4[0], w1 = w4[1];
            acc[0] = fmaf(av, w0.x, acc[0]);
            acc[1] = fmaf(av, w0.y, acc[1]);
            acc[2] = fmaf(av, w0.z, acc[2]);
            acc[3] = fmaf(av, w0.w, acc[3]);
            acc[4] = fmaf(av, w1.x, acc[4]);
            acc[5] = fmaf(av, w1.y, acc[5]);
            acc[6] = fmaf(av, w1.z, acc[6]);
            acc[7] = fmaf(av, w1.w, acc[7]);
        }
        float4* dst = reinterpret_cast<float4*>(T_ws + row * (DOUT * H) + d * H + q0);
        dst[0] = make_float4(acc[0], acc[1], acc[2], acc[3]);
        dst[1] = make_float4(acc[4], acc[5], acc[6], acc[7]);
    }
}

// -------- Kernel B: out[(row*512 + m)*128 + d] = b_out[d] + sum_q T[row][d][q]*bq[b,m][q] ----
// grid: 4096 blocks = (row 0..1023) x (m-tile 0..3, 128 m each), 256 threads.
// thread: d0 = (t&31)*4 (4 d per lane), ml = t>>5 (8 m-lanes),
// 16 passes over k: m = m0 + k*8 + ml.
__global__ __launch_bounds__(256) void kB(const float* __restrict__ bq_ws,
                                          const float* __restrict__ T_ws,
                                          const float* __restrict__ bout,
                                          float* __restrict__ out) {
    const int blk = blockIdx.x;
    const int row = blk >> 2;             // b*512 + n
    const int m0 = (blk & 3) * 128;
    const int bb = row >> 9;              // batch
    const int t = threadIdx.x;
    const int d0 = (t & 31) * 4;
    const int ml = t >> 5;

    // ---- T rows for my 4 d's into registers ----
    float Tr[4][16];
    const float4* Tv = reinterpret_cast<const float4*>(T_ws + row * (DOUT * H));
#pragma unroll
    for (int i = 0; i < 4; i++) {
#pragma unroll
        for (int h = 0; h < 4; h++) {
            const float4 u = Tv[(d0 + i) * 4 + h];
            Tr[i][h * 4 + 0] = u.x;
            Tr[i][h * 4 + 1] = u.y;
            Tr[i][h * 4 + 2] = u.z;
            Tr[i][h * 4 + 3] = u.w;
        }
    }

    float bo[4];
#pragma unroll
    for (int i = 0; i < 4; i++) bo[i] = bout[d0 + i];

#pragma unroll 4
    for (int k = 0; k < 16; k++) {
        const int m = m0 + k * 8 + ml;
        const float4* bqv = reinterpret_cast<const float4*>(bq_ws + (bb * N + m) * H);
        const float4 q0 = bqv[0], q1 = bqv[1], q2 = bqv[2], q3 = bqv[3];
        const float bv[16] = {q0.x, q0.y, q0.z, q0.w, q1.x, q1.y, q1.z, q1.w,
                              q2.x, q2.y, q2.z, q2.w, q3.x, q3.y, q3.z, q3.w};

        float acc[4] = {bo[0], bo[1], bo[2], bo[3]};
#pragma unroll
        for (int q = 0; q < 16; q++) {
#pragma unroll
            for (int i = 0; i < 4; i++) acc[i] = fmaf(bv[q], Tr[i][q], acc[i]);
        }

        float4* dst = reinterpret_cast<float4*>(out + (size_t)(row * N + m) * DOUT + d0);
        *dst = make_float4(acc[0], acc[1], acc[2], acc[3]);
    }
}

extern "C" void kernel_launch(void* const* d_in, const int* in_sizes, int n_in,
                              void* d_out, int out_size, void* d_ws, size_t ws_size,
                              hipStream_t stream) {
    const float* feats = (const float*)d_in[0];
    const float* gamma = (const float*)d_in[1];
    const float* beta  = (const float*)d_in[2];
    const float* Win   = (const float*)d_in[3];
    const float* bin   = (const float*)d_in[4];
    const float* Wout  = (const float*)d_in[5];
    const float* bout  = (const float*)d_in[6];

    float* bq_ws = (float*)d_ws;                                  // ROWS*16 fp32 = 64 KB
    float* T_ws  = (float*)((char*)d_ws + 64 * 1024);             // ROWS*128*16 fp32 = 8 MB

    kA<<<ROWS, 256, 0, stream>>>(feats, gamma, beta, Win, bin, Wout, bq_ws, T_ws);
    kB<<<ROWS * 4, 256, 0, stream>>>(bq_ws, T_ws, bout, (float*)d_out);
}

// Round 4
// 300.168 us; speedup vs baseline: 1.2702x; 1.2702x over previous
//
#include <hip/hip_runtime.h>

// Sizes (fixed by the problem)
#define B 2
#define N 512
#define DIN 256
#define H 16
#define DOUT 128
#define ROWS (B * N)   // 1024

typedef float f4 __attribute__((ext_vector_type(4)));  // clang vector: valid for nontemporal builtins

// -------- Kernel A: per row (b*512+n): LN + proj(a,bq) + T = a @ Wd --------
// Writes bq (fp32, ROWS x 16) and T (fp32, ROWS x 128 x 16) into workspace.
__global__ __launch_bounds__(256) void kA(const float* __restrict__ feats,
                                          const float* __restrict__ gamma,
                                          const float* __restrict__ beta,
                                          const float* __restrict__ Win,
                                          const float* __restrict__ bin,
                                          const float* __restrict__ Wout,
                                          float* __restrict__ bq_ws,
                                          float* __restrict__ T_ws) {
    const int row = blockIdx.x;       // 0..1023
    const int t = threadIdx.x;        // 0..255

    __shared__ float sx[DIN];         // normalized row
    __shared__ float pp[256];         // proj partials
    __shared__ float pa[H];           // a (first 16 of proj)
    __shared__ float redA[4], redB[4];

    // ---- load one element per thread, LayerNorm over 256 ----
    const float x = feats[row * DIN + t];

    float s = x;
#pragma unroll
    for (int o = 32; o; o >>= 1) s += __shfl_xor(s, o, 64);
    if ((t & 63) == 0) redA[t >> 6] = s;
    __syncthreads();
    const float mean = (redA[0] + redA[1] + redA[2] + redA[3]) * (1.0f / 256.0f);

    const float dx = x - mean;
    float s2 = dx * dx;
#pragma unroll
    for (int o = 32; o; o >>= 1) s2 += __shfl_xor(s2, o, 64);
    if ((t & 63) == 0) redB[t >> 6] = s2;
    __syncthreads();
    const float var = (redB[0] + redB[1] + redB[2] + redB[3]) * (1.0f / 256.0f);
    const float rstd = rsqrtf(var + 1e-5f);

    const float xn = dx * rstd * gamma[t] + beta[t];
    sx[t] = xn;
    __syncthreads();

    // ---- proj = xn @ Win (+ bin): 256 threads, k = t&31, seg = t>>5 ----
    {
        const int k = t & 31;
        const int seg = t >> 5;       // 8 segments of 32 j each
        const int j0 = seg * 32;
        float partial = 0.0f;
#pragma unroll
        for (int j = 0; j < 32; j++) {
            partial = fmaf(sx[j0 + j], Win[(j0 + j) * 32 + k], partial);
        }
        pp[t] = partial;
    }
    __syncthreads();

    if (t < 32) {
        float pr = bin[t];
#pragma unroll
        for (int h = 0; h < 8; h++) pr += pp[h * 32 + t];
        if (t < H) pa[t] = pr;                         // a
        else bq_ws[row * H + (t - H)] = pr;            // bq -> workspace
    }
    __syncthreads();

    // ---- T[d][q] = sum_p a[p] * Wout[d*256 + p*16 + q] ----
    // thread t: d = t>>1, q-half = (t&1)*8 -> 8 outputs
    {
        const int d = t >> 1;
        const int q0 = (t & 1) * 8;
        float acc[8];
#pragma unroll
        for (int j = 0; j < 8; j++) acc[j] = 0.0f;
        const float* wp = Wout + d * 256 + q0;
#pragma unroll
        for (int p = 0; p < 16; p++) {
            const float av = pa[p];
            const float4* w4 = reinterpret_cast<const float4*>(wp + p * 16);
            const float4 w0 = w4[0], w1 = w4[1];
            acc[0] = fmaf(av, w0.x, acc[0]);
            acc[1] = fmaf(av, w0.y, acc[1]);
            acc[2] = fmaf(av, w0.z, acc[2]);
            acc[3] = fmaf(av, w0.w, acc[3]);
            acc[4] = fmaf(av, w1.x, acc[4]);
            acc[5] = fmaf(av, w1.y, acc[5]);
            acc[6] = fmaf(av, w1.z, acc[6]);
            acc[7] = fmaf(av, w1.w, acc[7]);
        }
        float4* dst = reinterpret_cast<float4*>(T_ws + row * (DOUT * H) + d * H + q0);
        dst[0] = make_float4(acc[0], acc[1], acc[2], acc[3]);
        dst[1] = make_float4(acc[4], acc[5], acc[6], acc[7]);
    }
}

// -------- Kernel B: out[(row*512 + m)*128 + d] = b_out[d] + sum_q T[row][d][q]*bq[b,m][q] ----
// grid: 1024 blocks = one per row (b*512+n), 256 threads.
// thread: d0 = (t&31)*4 (4 d per lane), ml = t>>5 (8 m-lanes),
// 64 passes over k: m = k*8 + ml. Half-wave (32 lanes) stores one contiguous
// 512 B output row segment per k. Output is write-once streaming -> nontemporal.
__global__ __launch_bounds__(256) void kB(const float* __restrict__ bq_ws,
                                          const float* __restrict__ T_ws,
                                          const float* __restrict__ bout,
                                          float* __restrict__ out) {
    const int row = blockIdx.x;           // b*512 + n
    const int bb = row >> 9;              // batch
    const int t = threadIdx.x;
    const int d0 = (t & 31) * 4;
    const int ml = t >> 5;

    // ---- T rows for my 4 d's into registers (loaded once per block) ----
    float Tr[4][16];
    const float4* Tv = reinterpret_cast<const float4*>(T_ws + row * (DOUT * H));
#pragma unroll
    for (int i = 0; i < 4; i++) {
#pragma unroll
        for (int h = 0; h < 4; h++) {
            const float4 u = Tv[(d0 + i) * 4 + h];
            Tr[i][h * 4 + 0] = u.x;
            Tr[i][h * 4 + 1] = u.y;
            Tr[i][h * 4 + 2] = u.z;
            Tr[i][h * 4 + 3] = u.w;
        }
    }

    float bo[4];
#pragma unroll
    for (int i = 0; i < 4; i++) bo[i] = bout[d0 + i];

    const float* bq_base = bq_ws + (size_t)bb * N * H;
    float* out_base = out + (size_t)row * N * DOUT + d0;

#pragma unroll 4
    for (int k = 0; k < 64; k++) {
        const int m = k * 8 + ml;
        const float4* bqv = reinterpret_cast<const float4*>(bq_base + m * H);
        const float4 q0 = bqv[0], q1 = bqv[1], q2 = bqv[2], q3 = bqv[3];
        const float bv[16] = {q0.x, q0.y, q0.z, q0.w, q1.x, q1.y, q1.z, q1.w,
                              q2.x, q2.y, q2.z, q2.w, q3.x, q3.y, q3.z, q3.w};

        float acc[4] = {bo[0], bo[1], bo[2], bo[3]};
#pragma unroll
        for (int q = 0; q < 16; q++) {
#pragma unroll
            for (int i = 0; i < 4; i++) acc[i] = fmaf(bv[q], Tr[i][q], acc[i]);
        }

        f4 val = {acc[0], acc[1], acc[2], acc[3]};
        f4* dst = reinterpret_cast<f4*>(out_base + (size_t)m * DOUT);
        __builtin_nontemporal_store(val, dst);
    }
}

extern "C" void kernel_launch(void* const* d_in, const int* in_sizes, int n_in,
                              void* d_out, int out_size, void* d_ws, size_t ws_size,
                              hipStream_t stream) {
    const float* feats = (const float*)d_in[0];
    const float* gamma = (const float*)d_in[1];
    const float* beta  = (const float*)d_in[2];
    const float* Win   = (const float*)d_in[3];
    const float* bin   = (const float*)d_in[4];
    const float* Wout  = (const float*)d_in[5];
    const float* bout  = (const float*)d_in[6];

    float* bq_ws = (float*)d_ws;                                  // ROWS*16 fp32 = 64 KB
    float* T_ws  = (float*)((char*)d_ws + 64 * 1024);             // ROWS*128*16 fp32 = 8 MB

    kA<<<ROWS, 256, 0, stream>>>(feats, gamma, beta, Win, bin, Wout, bq_ws, T_ws);
    kB<<<ROWS, 256, 0, stream>>>(bq_ws, T_ws, bout, (float*)d_out);
}